// Round 5
// baseline (496.078 us; speedup 1.0000x reference)
//
#include <hip/hip_runtime.h>
#include <math.h>
#include <stdint.h>

#define EMBED 1024
#define HEADS 16
#define HDIM  64
#define BATCH 4
#define SEQL  2048
#define MROWS (BATCH*SEQL)   // 8192

typedef unsigned short u16;
typedef __bf16 bf16x8 __attribute__((ext_vector_type(8)));   // 4 VGPR MFMA operand
typedef float  f32x16 __attribute__((ext_vector_type(16)));  // 32x32 accumulator
typedef u16    u16x8  __attribute__((ext_vector_type(8)));

using gu32 = const __attribute__((address_space(1))) uint32_t;
using lu32 = __attribute__((address_space(3))) uint32_t;

#define LOG2E 1.44269504088896340736f

// fp32 -> bf16 via compiler cast (emits v_cvt_pk_bf16_f32, RNE)
__device__ __forceinline__ u16 f2b(float f) {
  union { __bf16 h; u16 u; } c; c.h = (__bf16)f; return c.u;
}
__device__ __forceinline__ uint32_t pk2(float lo, float hi) {
  union { __bf16 h[2]; uint32_t u; } c;
  c.h[0] = (__bf16)lo; c.h[1] = (__bf16)hi;
  return c.u;
}

// ---------------------------------------------------------------------------
// fp32 -> bf16 conversion (vectorized, grid-stride)
// ---------------------------------------------------------------------------
__global__ void cvt_bf16(const float* __restrict__ in, u16* __restrict__ out, int n4) {
  int i = blockIdx.x * blockDim.x + threadIdx.x;
  const int stride = gridDim.x * blockDim.x;
  for (; i < n4; i += stride) {
    float4 v = reinterpret_cast<const float4*>(in)[i];
    uint2 o; o.x = pk2(v.x, v.y); o.y = pk2(v.z, v.w);
    reinterpret_cast<uint2*>(out)[i] = o;
  }
}

// ---------------------------------------------------------------------------
// bf16 MFMA GEMM core: C[m][n] = (sum_k A[m][k]*W[n][k] + bias[n]) * scale
// 512 threads = 8 waves (2M x 4N); per wave 64x32 output = 2x1 frags of 32x32.
// Tile 128x128, BK=64. Staging via global_load_lds width-16, linear LDS.
// MODE 0: fp32 out row-major.  MODE 1: bf16 out in (B,H,T,D).
// ---------------------------------------------------------------------------
template<int MODE>
__device__ __forceinline__ void gemm_core(const u16* __restrict__ A,
                                          const u16* __restrict__ W,
                                          const float* __restrict__ bias,
                                          void* __restrict__ outp, float scale,
                                          u16* As, u16* Bs)
{
  const int tid  = threadIdx.x;
  const int lane = tid & 63;
  const int wid  = tid >> 6;          // 0..7
  const int wm = wid >> 2, wn = wid & 3;
  const int l31 = lane & 31, hh = lane >> 5;
  const int bm = blockIdx.x * 128, bn = blockIdx.y * 128;

  f32x16 acc[2] = {};

  for (int k0 = 0; k0 < EMBED; k0 += 64) {
    __syncthreads();
#pragma unroll
    for (int r = 0; r < 2; ++r) {
      const int u = tid + r * 512;          // 16B chunk id: row = u>>3, c = u&7
      const int row = u >> 3, c = u & 7;
      __builtin_amdgcn_global_load_lds(
          (gu32*)(A + (size_t)(bm + row) * EMBED + k0 + c * 8),
          (lu32*)(As + (size_t)u * 8), 16, 0, 0);
      __builtin_amdgcn_global_load_lds(
          (gu32*)(W + (size_t)(bn + row) * EMBED + k0 + c * 8),
          (lu32*)(Bs + (size_t)u * 8), 16, 0, 0);
    }
    __syncthreads();   // compiler drains vmcnt before barrier

#pragma unroll
    for (int g = 0; g < 4; ++g) {           // k-group of 16
      bf16x8 af[2], bfr;
#pragma unroll
      for (int it = 0; it < 2; ++it) {
        const int row = wm * 64 + it * 32 + l31;
        af[it] = *reinterpret_cast<const bf16x8*>(As + row * 64 + g * 16 + hh * 8);
      }
      {
        const int row = wn * 32 + l31;
        bfr = *reinterpret_cast<const bf16x8*>(Bs + row * 64 + g * 16 + hh * 8);
      }
#pragma unroll
      for (int it = 0; it < 2; ++it)
        acc[it] = __builtin_amdgcn_mfma_f32_32x32x16_bf16(af[it], bfr, acc[it], 0, 0, 0);
    }
  }

  // D layout (32x32): row=(reg&3)+8*(reg>>2)+4*(lane>>5), col=lane&31
  const int n = bn + wn * 32 + l31;
  const float bv = bias[n];
#pragma unroll
  for (int it = 0; it < 2; ++it) {
#pragma unroll
    for (int reg = 0; reg < 16; ++reg) {
      const int m = bm + wm * 64 + it * 32 + (reg & 3) + 8 * (reg >> 2) + 4 * hh;
      const float val = (acc[it][reg] + bv) * scale;
      if (MODE == 0) {
        ((float*)outp)[(size_t)m * EMBED + n] = val;
      } else {
        const int b = m >> 11, t = m & (SEQL - 1);
        const int h = n >> 6,  d = n & (HDIM - 1);
        ((u16*)outp)[(((size_t)(b * HEADS + h)) * SEQL + t) * HDIM + d] = f2b(val);
      }
    }
  }
}

// Batched Q/K/V projection: blockIdx.z selects the (A, W, bias, out, scale) set.
__global__ __launch_bounds__(512)
void gemm_qkv(const u16* __restrict__ A0, const u16* __restrict__ A1, const u16* __restrict__ A2,
              const u16* __restrict__ W0, const u16* __restrict__ W1, const u16* __restrict__ W2,
              const float* __restrict__ b0, const float* __restrict__ b1, const float* __restrict__ b2,
              u16* __restrict__ o0, u16* __restrict__ o1, u16* __restrict__ o2,
              float s0)
{
  __shared__ __attribute__((aligned(16))) u16 As[128 * 64];
  __shared__ __attribute__((aligned(16))) u16 Bs[128 * 64];
  const int z = blockIdx.z;
  const u16*   A = (z == 0) ? A0 : (z == 1) ? A1 : A2;
  const u16*   W = (z == 0) ? W0 : (z == 1) ? W1 : W2;
  const float* b = (z == 0) ? b0 : (z == 1) ? b1 : b2;
  u16*         o = (z == 0) ? o0 : (z == 1) ? o1 : o2;
  const float  s = (z == 0) ? s0 : 1.f;
  gemm_core<1>(A, W, b, o, s, As, Bs);
}

__global__ __launch_bounds__(512)
void gemm_out(const u16* __restrict__ A, const u16* __restrict__ W,
              const float* __restrict__ bias, float* __restrict__ outp)
{
  __shared__ __attribute__((aligned(16))) u16 As[128 * 64];
  __shared__ __attribute__((aligned(16))) u16 Bs[128 * 64];
  gemm_core<0>(A, W, bias, outp, 1.f, As, Bs);
}

// ---------------------------------------------------------------------------
// Flash attention, bf16 MFMA, transposed-S structure, base-2 online softmax.
// Q projection carries scale 0.125*log2e, so S' = S*log2e and p = exp2(s'-m').
// Grid (T/128, B*H); 256 thr = 4 waves; wave wq owns q rows wq*32..+31.
// S^T = mfma(K, Q) -> lane owns ONE q-row; defer-max (THR=8): skip oacc
// rescale while the running max drifts < 8 (P bounded by 2^8, fp32 absorbs).
// ---------------------------------------------------------------------------
__global__ __launch_bounds__(256)
void attn_mfma(const u16* __restrict__ Qp, const u16* __restrict__ Kp,
               const u16* __restrict__ Vp, u16* __restrict__ Ob)
{
  __shared__ __attribute__((aligned(16))) u16 smem[128 * 66]; // 16.9 KB
  u16* Ks = smem;          // [64][64] swizzled   (8 KB)
  u16* Vt = smem + 4096;   // [64][64] transposed (8 KB)

  const int tid  = threadIdx.x;
  const int lane = tid & 63;
  const int wq   = tid >> 6;
  const int l31  = lane & 31, hh = lane >> 5;
  const int bh   = blockIdx.y;
  const int q0   = blockIdx.x * 128;
  const size_t kvbase = (size_t)bh * SEQL * HDIM;

  // Q fragments in registers (B-operand of mfma(K,Q)): t = q0+wq*32+l31
  bf16x8 qf[4];
  {
    const u16* qrow = Qp + kvbase + (size_t)(q0 + wq * 32 + l31) * HDIM;
#pragma unroll
    for (int g = 0; g < 4; ++g)
      qf[g] = *reinterpret_cast<const bf16x8*>(qrow + g * 16 + hh * 8);
  }

  float mrow = -INFINITY, lrow = 0.f;
  f32x16 oacc[2] = {};     // O^T tiles: d 0..31, 32..63 (col = own q-row)

  for (int s0 = 0; s0 < SEQL; s0 += 64) {
    __syncthreads();       // previous step done reading Ks/Vt
    // --- stage K via global_load_lds, source pre-swizzled (chunk ^= s&7) ---
#pragma unroll
    for (int r = 0; r < 2; ++r) {
      const int u = tid + r * 256;
      const int s = u >> 3, cc = u & 7;
      const int cg = cc ^ (s & 7);
      __builtin_amdgcn_global_load_lds(
          (gu32*)(Kp + kvbase + (size_t)(s0 + s) * HDIM + cg * 8),
          (lu32*)(Ks + (size_t)u * 8), 16, 0, 0);
    }
    // --- stage V: reg load + transposed swizzled LDS writes ---
    u16x8 vreg[2];
#pragma unroll
    for (int r = 0; r < 2; ++r) {
      const int u = tid + r * 256;
      const int s = u >> 3, c = u & 7;
      vreg[r] = *reinterpret_cast<const u16x8*>(Vp + kvbase + (size_t)(s0 + s) * HDIM + c * 8);
    }
#pragma unroll
    for (int r = 0; r < 2; ++r) {
      const int u = tid + r * 256;
      const int s = u >> 3, c = u & 7;
#pragma unroll
      for (int e = 0; e < 8; ++e) {
        const int d = c * 8 + e;
        const int slot = (s >> 3) ^ (d & 7) ^ (d >> 3);
        Vt[d * 64 + slot * 8 + (s & 7)] = vreg[r][e];
      }
    }
    __syncthreads();       // drains gload_lds + ds_writes

    // --- S^T = mfma(K, Q): rows s (2 tiles of 32), col = own q-row ---
    f32x16 st[2] = {};
#pragma unroll
    for (int ts = 0; ts < 2; ++ts) {
      const int srow = ts * 32 + l31;
#pragma unroll
      for (int g = 0; g < 4; ++g) {
        const int slot = (g * 2 + hh) ^ (srow & 7);
        bf16x8 kf = *reinterpret_cast<const bf16x8*>(Ks + srow * 64 + slot * 8);
        st[ts] = __builtin_amdgcn_mfma_f32_32x32x16_bf16(kf, qf[g], st[ts], 0, 0, 0);
      }
    }

    // --- online softmax (base 2, defer-max): row t = l31 lives in-lane ---
    float mx = -INFINITY;
#pragma unroll
    for (int ts = 0; ts < 2; ++ts)
#pragma unroll
      for (int rg = 0; rg < 16; ++rg) mx = fmaxf(mx, st[ts][rg]);
    mx = fmaxf(mx, __shfl_xor(mx, 32));
    if (!__all(mx <= mrow + 8.f)) {
      const float mnew = fmaxf(mrow, mx);
      const float alpha = __builtin_amdgcn_exp2f(mrow - mnew);
      lrow *= alpha;
#pragma unroll
      for (int jd = 0; jd < 2; ++jd)
#pragma unroll
        for (int rg = 0; rg < 16; ++rg) oacc[jd][rg] *= alpha;
      mrow = mnew;
    }
    float rsum = 0.f;
#pragma unroll
    for (int ts = 0; ts < 2; ++ts)
#pragma unroll
      for (int rg = 0; rg < 16; ++rg) {
        const float p = __builtin_amdgcn_exp2f(st[ts][rg] - mrow);
        st[ts][rg] = p;
        rsum += p;
      }
    rsum += __shfl_xor(rsum, 32);
    lrow += rsum;

    // --- P^T B-frags: s-group gs holds s = gs*16 + hh*8 + i ---
    bf16x8 pb[4];
#pragma unroll
    for (int ts = 0; ts < 2; ++ts)
#pragma unroll
      for (int gl = 0; gl < 2; ++gl) {
        const int rb = gl * 8;
        const uint32_t A0 = pk2(st[ts][rb + 0], st[ts][rb + 1]);
        const uint32_t A1 = pk2(st[ts][rb + 2], st[ts][rb + 3]);
        const uint32_t B0 = pk2(st[ts][rb + 4], st[ts][rb + 5]);
        const uint32_t B1 = pk2(st[ts][rb + 6], st[ts][rb + 7]);
        const uint32_t sA0 = __shfl_xor(A0, 32);
        const uint32_t sA1 = __shfl_xor(A1, 32);
        const uint32_t sB0 = __shfl_xor(B0, 32);
        const uint32_t sB1 = __shfl_xor(B1, 32);
        union { uint32_t w[4]; bf16x8 v; } f;
        f.w[0] = hh ? sB0 : A0;
        f.w[1] = hh ? sB1 : A1;
        f.w[2] = hh ? B0  : sA0;
        f.w[3] = hh ? B1  : sA1;
        pb[ts * 2 + gl] = f.v;
      }

    // --- O^T += mfma(V^T, P^T) ---
#pragma unroll
    for (int gs = 0; gs < 4; ++gs)
#pragma unroll
      for (int jd = 0; jd < 2; ++jd) {
        const int drow = jd * 32 + l31;
        const int slot = (gs * 2 + hh) ^ (drow & 7) ^ (drow >> 3);
        bf16x8 vf = *reinterpret_cast<const bf16x8*>(Vt + drow * 64 + slot * 8);
        oacc[jd] = __builtin_amdgcn_mfma_f32_32x32x16_bf16(vf, pb[gs], oacc[jd], 0, 0, 0);
      }
  }

  // --- epilogue: normalize, transpose via LDS, coalesced bf16 store ---
  __syncthreads();                 // done with Ks/Vt; reuse smem as Os[128][66]
  u16* Os = smem;
  const float inv = 1.f / lrow;
  const int trow = wq * 32 + l31;
#pragma unroll
  for (int jd = 0; jd < 2; ++jd)
#pragma unroll
    for (int q = 0; q < 4; ++q) {
      const int dbase = jd * 32 + 8 * q + 4 * hh;
      const uint32_t w0 = pk2(oacc[jd][q * 4 + 0] * inv, oacc[jd][q * 4 + 1] * inv);
      const uint32_t w1 = pk2(oacc[jd][q * 4 + 2] * inv, oacc[jd][q * 4 + 3] * inv);
      *reinterpret_cast<uint32_t*>(Os + trow * 66 + dbase)     = w0;
      *reinterpret_cast<uint32_t*>(Os + trow * 66 + dbase + 2) = w1;
    }
  __syncthreads();
  const int b = bh >> 4, h = bh & 15;
#pragma unroll
  for (int r = 0; r < 4; ++r) {
    const int u = tid + r * 256;
    const int row = u >> 3, c = u & 7;
    uint32_t wds[4];
#pragma unroll
    for (int i2 = 0; i2 < 4; ++i2)
      wds[i2] = *reinterpret_cast<const uint32_t*>(Os + row * 66 + c * 8 + i2 * 2);
    uint4 ov; ov.x = wds[0]; ov.y = wds[1]; ov.z = wds[2]; ov.w = wds[3];
    *reinterpret_cast<uint4*>(Ob + ((size_t)(b * SEQL + q0 + row)) * EMBED + h * 64 + c * 8) = ov;
  }
}

// ---------------------------------------------------------------------------
extern "C" void kernel_launch(void* const* d_in, const int* in_sizes, int n_in,
                              void* d_out, int out_size, void* d_ws, size_t ws_size,
                              hipStream_t stream)
{
  const float* query = (const float*)d_in[0];
  const float* key   = (const float*)d_in[1];
  const float* value = (const float*)d_in[2];
  const float* Wq    = (const float*)d_in[3];
  const float* bq    = (const float*)d_in[4];
  const float* Wk    = (const float*)d_in[5];
  const float* bk    = (const float*)d_in[6];
  const float* Wv    = (const float*)d_in[7];
  const float* bv    = (const float*)d_in[8];
  const float* Wo    = (const float*)d_in[9];
  const float* bo    = (const float*)d_in[10];
  float* out = (float*)d_out;

  const size_t NBIG = (size_t)1 << 23;   // 8192*1024
  const size_t NW   = (size_t)1 << 20;   // 1024*1024
  u16* Xq  = (u16*)d_ws;
  u16* Xk  = Xq  + NBIG;
  u16* Xv  = Xk  + NBIG;
  u16* Wqb = Xv  + NBIG;
  u16* Wkb = Wqb + NW;
  u16* Wvb = Wkb + NW;
  u16* Wob = Wvb + NW;
  u16* Qb  = Wob + NW;
  u16* Kb  = Qb  + NBIG;
  u16* Vb  = Kb  + NBIG;
  u16* Oa  = Vb  + NBIG;                 // total 120 MiB

  cvt_bf16<<<2048, 256, 0, stream>>>(query, Xq, (int)(NBIG / 4));
  cvt_bf16<<<2048, 256, 0, stream>>>(key,   Xk, (int)(NBIG / 4));
  cvt_bf16<<<2048, 256, 0, stream>>>(value, Xv, (int)(NBIG / 4));
  cvt_bf16<<<512,  256, 0, stream>>>(Wq, Wqb, (int)(NW / 4));
  cvt_bf16<<<512,  256, 0, stream>>>(Wk, Wkb, (int)(NW / 4));
  cvt_bf16<<<512,  256, 0, stream>>>(Wv, Wvb, (int)(NW / 4));
  cvt_bf16<<<512,  256, 0, stream>>>(Wo, Wob, (int)(NW / 4));

  // batched QKV projection: one dispatch, grid.z selects the set
  gemm_qkv<<<dim3(MROWS / 128, EMBED / 128, 3), 512, 0, stream>>>(
      Xq, Xk, Xv, Wqb, Wkb, Wvb, bq, bk, bv, Qb, Kb, Vb,
      0.125f * LOG2E);   // fold softmax scale + log2e into Q

  attn_mfma<<<dim3(SEQL / 128, BATCH * HEADS), 256, 0, stream>>>(Qb, Kb, Vb, Oa);

  gemm_out<<<dim3(MROWS / 128, EMBED / 128), 512, 0, stream>>>(Oa, Wob, bo, out);
}

// Round 7
// 430.666 us; speedup vs baseline: 1.1519x; 1.1519x over previous
//
#include <hip/hip_runtime.h>
#include <math.h>
#include <stdint.h>

#define EMBED 1024
#define HEADS 16
#define HDIM  64
#define BATCH 4
#define SEQL  2048
#define MROWS (BATCH*SEQL)   // 8192

typedef unsigned short u16;
typedef __bf16 bf16x8 __attribute__((ext_vector_type(8)));   // 4 VGPR MFMA operand
typedef float  f32x16 __attribute__((ext_vector_type(16)));  // 32x32 accumulator
typedef u16    u16x8  __attribute__((ext_vector_type(8)));

using gu32 = const __attribute__((address_space(1))) uint32_t;
using lu32 = __attribute__((address_space(3))) uint32_t;

#define LOG2E 1.44269504088896340736f

// fp32 -> bf16 via compiler cast (emits v_cvt_pk_bf16_f32, RNE)
__device__ __forceinline__ u16 f2b(float f) {
  union { __bf16 h; u16 u; } c; c.h = (__bf16)f; return c.u;
}
__device__ __forceinline__ uint32_t pk2(float lo, float hi) {
  union { __bf16 h[2]; uint32_t u; } c;
  c.h[0] = (__bf16)lo; c.h[1] = (__bf16)hi;
  return c.u;
}

// ---------------------------------------------------------------------------
// fp32 -> bf16 conversion (vectorized, grid-stride)
// ---------------------------------------------------------------------------
__global__ void cvt_bf16(const float* __restrict__ in, u16* __restrict__ out, int n4) {
  int i = blockIdx.x * blockDim.x + threadIdx.x;
  const int stride = gridDim.x * blockDim.x;
  for (; i < n4; i += stride) {
    float4 v = reinterpret_cast<const float4*>(in)[i];
    uint2 o; o.x = pk2(v.x, v.y); o.y = pk2(v.z, v.w);
    reinterpret_cast<uint2*>(out)[i] = o;
  }
}

// ---------------------------------------------------------------------------
// bf16 MFMA GEMM core: C[m][n] = (sum_k A[m][k]*W[n][k] + bias[n]) * scale
// 256 threads = 4 waves (2x2); per wave 64x64 = 2x2 frags of 32x32
// (1.0 LDS-read per MFMA — round-3 proven geometry).
// Tile 128x128, BK=64. Staging via global_load_lds width-16, linear LDS.
// MODE 0: fp32 out row-major.  MODE 1: bf16 out in (B,H,T,D).
// ---------------------------------------------------------------------------
template<int MODE>
__device__ __forceinline__ void gemm_core(const u16* __restrict__ A,
                                          const u16* __restrict__ W,
                                          const float* __restrict__ bias,
                                          void* __restrict__ outp, float scale,
                                          u16* As, u16* Bs)
{
  const int tid  = threadIdx.x;
  const int lane = tid & 63;
  const int wid  = tid >> 6;
  const int wm = wid >> 1, wn = wid & 1;
  const int l31 = lane & 31, hh = lane >> 5;
  const int bm = blockIdx.x * 128, bn = blockIdx.y * 128;

  f32x16 acc[2][2] = {};

  for (int k0 = 0; k0 < EMBED; k0 += 64) {
    __syncthreads();
#pragma unroll
    for (int r = 0; r < 4; ++r) {
      const int u = tid + r * 256;          // 16B chunk id: row = u>>3, c = u&7
      const int row = u >> 3, c = u & 7;
      __builtin_amdgcn_global_load_lds(
          (gu32*)(A + (size_t)(bm + row) * EMBED + k0 + c * 8),
          (lu32*)(As + (size_t)u * 8), 16, 0, 0);
      __builtin_amdgcn_global_load_lds(
          (gu32*)(W + (size_t)(bn + row) * EMBED + k0 + c * 8),
          (lu32*)(Bs + (size_t)u * 8), 16, 0, 0);
    }
    __syncthreads();   // compiler drains vmcnt before barrier

#pragma unroll
    for (int g = 0; g < 4; ++g) {           // k-group of 16
      bf16x8 af[2], bfr[2];
#pragma unroll
      for (int it = 0; it < 2; ++it) {
        const int row = wm * 64 + it * 32 + l31;
        af[it] = *reinterpret_cast<const bf16x8*>(As + row * 64 + g * 16 + hh * 8);
      }
#pragma unroll
      for (int jt = 0; jt < 2; ++jt) {
        const int row = wn * 64 + jt * 32 + l31;
        bfr[jt] = *reinterpret_cast<const bf16x8*>(Bs + row * 64 + g * 16 + hh * 8);
      }
#pragma unroll
      for (int it = 0; it < 2; ++it)
#pragma unroll
        for (int jt = 0; jt < 2; ++jt)
          acc[it][jt] = __builtin_amdgcn_mfma_f32_32x32x16_bf16(af[it], bfr[jt], acc[it][jt], 0, 0, 0);
    }
  }

  // D layout (32x32): row=(reg&3)+8*(reg>>2)+4*(lane>>5), col=lane&31
#pragma unroll
  for (int it = 0; it < 2; ++it)
#pragma unroll
    for (int jt = 0; jt < 2; ++jt) {
      const int n = bn + wn * 64 + jt * 32 + l31;
      const float bv = bias[n];
#pragma unroll
      for (int reg = 0; reg < 16; ++reg) {
        const int m = bm + wm * 64 + it * 32 + (reg & 3) + 8 * (reg >> 2) + 4 * hh;
        const float val = (acc[it][jt][reg] + bv) * scale;
        if (MODE == 0) {
          ((float*)outp)[(size_t)m * EMBED + n] = val;
        } else {
          const int b = m >> 11, t = m & (SEQL - 1);
          const int h = n >> 6,  d = n & (HDIM - 1);
          ((u16*)outp)[(((size_t)(b * HEADS + h)) * SEQL + t) * HDIM + d] = f2b(val);
        }
      }
    }
}

// Batched Q/K/V projection: blockIdx.z selects the (A, W, bias, out, scale) set.
__global__ __launch_bounds__(256)
void gemm_qkv(const u16* __restrict__ A0, const u16* __restrict__ A1, const u16* __restrict__ A2,
              const u16* __restrict__ W0, const u16* __restrict__ W1, const u16* __restrict__ W2,
              const float* __restrict__ b0, const float* __restrict__ b1, const float* __restrict__ b2,
              u16* __restrict__ o0, u16* __restrict__ o1, u16* __restrict__ o2,
              float s0)
{
  __shared__ __attribute__((aligned(16))) u16 As[128 * 64];
  __shared__ __attribute__((aligned(16))) u16 Bs[128 * 64];
  const int z = blockIdx.z;
  const u16*   A = (z == 0) ? A0 : (z == 1) ? A1 : A2;
  const u16*   W = (z == 0) ? W0 : (z == 1) ? W1 : W2;
  const float* b = (z == 0) ? b0 : (z == 1) ? b1 : b2;
  u16*         o = (z == 0) ? o0 : (z == 1) ? o1 : o2;
  const float  s = (z == 0) ? s0 : 1.f;
  gemm_core<1>(A, W, b, o, s, As, Bs);
}

__global__ __launch_bounds__(256)
void gemm_out(const u16* __restrict__ A, const u16* __restrict__ W,
              const float* __restrict__ bias, float* __restrict__ outp)
{
  __shared__ __attribute__((aligned(16))) u16 As[128 * 64];
  __shared__ __attribute__((aligned(16))) u16 Bs[128 * 64];
  gemm_core<0>(A, W, bias, outp, 1.f, As, Bs);
}

// ---------------------------------------------------------------------------
// Flash attention, bf16 MFMA, transposed-S, base-2 softmax, 2-phase pipeline.
// Double-buffered K/V LDS (32 KB): tile t+1's K gload_lds + V reg-loads are
// issued BEFORE tile t's compute; V ds_writes land after softmax (T14 split);
// ONE barrier per tile. Softmax reductions are pairwise trees (depth 5).
// ---------------------------------------------------------------------------
__global__ __launch_bounds__(256, 4)
void attn_mfma(const u16* __restrict__ Qp, const u16* __restrict__ Kp,
               const u16* __restrict__ Vp, u16* __restrict__ Ob)
{
  __shared__ __attribute__((aligned(16))) u16 smem[16384]; // 32 KB: 2 x (Ks 8KB + Vt 8KB)

  const int tid  = threadIdx.x;
  const int lane = tid & 63;
  const int wq   = tid >> 6;
  const int l31  = lane & 31, hh = lane >> 5;
  const int bh   = blockIdx.y;
  const int q0   = blockIdx.x * 128;
  const size_t kvbase = (size_t)bh * SEQL * HDIM;

  // Q fragments in registers (B-operand of mfma(K,Q)): t = q0+wq*32+l31
  bf16x8 qf[4];
  {
    const u16* qrow = Qp + kvbase + (size_t)(q0 + wq * 32 + l31) * HDIM;
#pragma unroll
    for (int g = 0; g < 4; ++g)
      qf[g] = *reinterpret_cast<const bf16x8*>(qrow + g * 16 + hh * 8);
  }

  float mrow = -INFINITY, lrow = 0.f;
  f32x16 oacc[2] = {};     // O^T tiles: d 0..31, 32..63 (col = own q-row)

  // --- prologue: stage tile 0 into buffer 0 ---
  {
#pragma unroll
    for (int r = 0; r < 2; ++r) {
      const int u = tid + r * 256;
      const int s = u >> 3, cc = u & 7;
      const int cg = cc ^ (s & 7);
      __builtin_amdgcn_global_load_lds(
          (gu32*)(Kp + kvbase + (size_t)s * HDIM + cg * 8),
          (lu32*)(smem + (size_t)u * 8), 16, 0, 0);
    }
#pragma unroll
    for (int r = 0; r < 2; ++r) {
      const int u = tid + r * 256;
      const int s = u >> 3, c = u & 7;
      const u16x8 v = *reinterpret_cast<const u16x8*>(Vp + kvbase + (size_t)s * HDIM + c * 8);
#pragma unroll
      for (int e = 0; e < 8; ++e) {
        const int d = c * 8 + e;
        const int slot = (s >> 3) ^ (d & 7) ^ (d >> 3);
        smem[4096 + d * 64 + slot * 8 + (s & 7)] = v[e];
      }
    }
  }
  __syncthreads();

  const int NT = SEQL / 64;   // 32
  for (int t = 0; t < NT; ++t) {
    const int cur = t & 1;
    const u16* Kc = smem + cur * 8192;
    const u16* Vc = smem + cur * 8192 + 4096;
    u16* Kn = smem + (cur ^ 1) * 8192;
    u16* Vn = smem + (cur ^ 1) * 8192 + 4096;
    const bool pf = (t + 1 < NT);

    // --- issue next tile's K gload_lds + V reg loads (land under compute) ---
    u16x8 vreg[2];
    if (pf) {
      const int sb = (t + 1) * 64;
#pragma unroll
      for (int r = 0; r < 2; ++r) {
        const int u = tid + r * 256;
        const int s = u >> 3, cc = u & 7;
        const int cg = cc ^ (s & 7);
        __builtin_amdgcn_global_load_lds(
            (gu32*)(Kp + kvbase + (size_t)(sb + s) * HDIM + cg * 8),
            (lu32*)(Kn + (size_t)u * 8), 16, 0, 0);
      }
#pragma unroll
      for (int r = 0; r < 2; ++r) {
        const int u = tid + r * 256;
        const int s = u >> 3, c = u & 7;
        vreg[r] = *reinterpret_cast<const u16x8*>(Vp + kvbase + (size_t)(sb + s) * HDIM + c * 8);
      }
    }

    // --- S^T = mfma(K, Q): g outer / ts inner -> 2 independent chains ---
    f32x16 st[2] = {};
    __builtin_amdgcn_s_setprio(1);
#pragma unroll
    for (int g = 0; g < 4; ++g)
#pragma unroll
      for (int ts = 0; ts < 2; ++ts) {
        const int srow = ts * 32 + l31;
        const int slot = (g * 2 + hh) ^ (srow & 7);
        bf16x8 kf = *reinterpret_cast<const bf16x8*>(Kc + srow * 64 + slot * 8);
        st[ts] = __builtin_amdgcn_mfma_f32_32x32x16_bf16(kf, qf[g], st[ts], 0, 0, 0);
      }
    __builtin_amdgcn_s_setprio(0);

    // --- online softmax (base 2, defer-max), tree reductions (depth 5) ---
    float red[16];
#pragma unroll
    for (int r = 0; r < 16; ++r) red[r] = fmaxf(st[0][r], st[1][r]);
#pragma unroll
    for (int off = 8; off >= 1; off >>= 1)
#pragma unroll
      for (int r = 0; r < off; ++r) red[r] = fmaxf(red[r], red[r + off]);
    const float mx = fmaxf(red[0], __shfl_xor(red[0], 32));
    if (!__all(mx <= mrow + 8.f)) {
      const float mnew = fmaxf(mrow, mx);
      const float alpha = __builtin_amdgcn_exp2f(mrow - mnew);
      lrow *= alpha;
#pragma unroll
      for (int jd = 0; jd < 2; ++jd)
#pragma unroll
        for (int rg = 0; rg < 16; ++rg) oacc[jd][rg] *= alpha;
      mrow = mnew;
    }
#pragma unroll
    for (int ts = 0; ts < 2; ++ts)
#pragma unroll
      for (int rg = 0; rg < 16; ++rg)
        st[ts][rg] = __builtin_amdgcn_exp2f(st[ts][rg] - mrow);
    float sr[16];
#pragma unroll
    for (int r = 0; r < 16; ++r) sr[r] = st[0][r] + st[1][r];
#pragma unroll
    for (int off = 8; off >= 1; off >>= 1)
#pragma unroll
      for (int r = 0; r < off; ++r) sr[r] += sr[r + off];
    lrow += sr[0] + __shfl_xor(sr[0], 32);

    // --- write-late: V(t+1) regs -> LDS (loads have landed under compute) ---
    if (pf) {
#pragma unroll
      for (int r = 0; r < 2; ++r) {
        const int u = tid + r * 256;
        const int s = u >> 3, c = u & 7;
#pragma unroll
        for (int e = 0; e < 8; ++e) {
          const int d = c * 8 + e;
          const int slot = (s >> 3) ^ (d & 7) ^ (d >> 3);
          Vn[d * 64 + slot * 8 + (s & 7)] = vreg[r][e];
        }
      }
    }

    // --- P^T B-frags: s-group gs holds s = gs*16 + hh*8 + i ---
    bf16x8 pb[4];
#pragma unroll
    for (int ts = 0; ts < 2; ++ts)
#pragma unroll
      for (int gl = 0; gl < 2; ++gl) {
        const int rb = gl * 8;
        const uint32_t A0 = pk2(st[ts][rb + 0], st[ts][rb + 1]);
        const uint32_t A1 = pk2(st[ts][rb + 2], st[ts][rb + 3]);
        const uint32_t B0 = pk2(st[ts][rb + 4], st[ts][rb + 5]);
        const uint32_t B1 = pk2(st[ts][rb + 6], st[ts][rb + 7]);
        const uint32_t sA0 = __shfl_xor(A0, 32);
        const uint32_t sA1 = __shfl_xor(A1, 32);
        const uint32_t sB0 = __shfl_xor(B0, 32);
        const uint32_t sB1 = __shfl_xor(B1, 32);
        union { uint32_t w[4]; bf16x8 v; } f;
        f.w[0] = hh ? sB0 : A0;
        f.w[1] = hh ? sB1 : A1;
        f.w[2] = hh ? B0  : sA0;
        f.w[3] = hh ? B1  : sA1;
        pb[ts * 2 + gl] = f.v;
      }

    // --- O^T += mfma(V^T, P^T): jd inner -> 2 independent chains ---
    __builtin_amdgcn_s_setprio(1);
#pragma unroll
    for (int gs = 0; gs < 4; ++gs)
#pragma unroll
      for (int jd = 0; jd < 2; ++jd) {
        const int drow = jd * 32 + l31;
        const int slot = (gs * 2 + hh) ^ (drow & 7) ^ (drow >> 3);
        bf16x8 vf = *reinterpret_cast<const bf16x8*>(Vc + drow * 64 + slot * 8);
        oacc[jd] = __builtin_amdgcn_mfma_f32_32x32x16_bf16(vf, pb[gs], oacc[jd], 0, 0, 0);
      }
    __builtin_amdgcn_s_setprio(0);

    __syncthreads();   // drains K gload_lds (nxt) + orders V writes/reads
  }

  // --- epilogue: normalize, transpose via LDS, coalesced bf16 store ---
  u16* Os = smem;                  // 128*66 u16 = 16.5 KB <= 32 KB
  const float inv = 1.f / lrow;
  const int trow = wq * 32 + l31;
#pragma unroll
  for (int jd = 0; jd < 2; ++jd)
#pragma unroll
    for (int q = 0; q < 4; ++q) {
      const int dbase = jd * 32 + 8 * q + 4 * hh;
      const uint32_t w0 = pk2(oacc[jd][q * 4 + 0] * inv, oacc[jd][q * 4 + 1] * inv);
      const uint32_t w1 = pk2(oacc[jd][q * 4 + 2] * inv, oacc[jd][q * 4 + 3] * inv);
      *reinterpret_cast<uint32_t*>(Os + trow * 66 + dbase)     = w0;
      *reinterpret_cast<uint32_t*>(Os + trow * 66 + dbase + 2) = w1;
    }
  __syncthreads();
  const int b = bh >> 4, h = bh & 15;
#pragma unroll
  for (int r = 0; r < 4; ++r) {
    const int u = tid + r * 256;
    const int row = u >> 3, c = u & 7;
    uint32_t wds[4];
#pragma unroll
    for (int i2 = 0; i2 < 4; ++i2)
      wds[i2] = *reinterpret_cast<const uint32_t*>(Os + row * 66 + c * 8 + i2 * 2);
    uint4 ov; ov.x = wds[0]; ov.y = wds[1]; ov.z = wds[2]; ov.w = wds[3];
    *reinterpret_cast<uint4*>(Ob + ((size_t)(b * SEQL + q0 + row)) * EMBED + h * 64 + c * 8) = ov;
  }
}

// ---------------------------------------------------------------------------
extern "C" void kernel_launch(void* const* d_in, const int* in_sizes, int n_in,
                              void* d_out, int out_size, void* d_ws, size_t ws_size,
                              hipStream_t stream)
{
  const float* query = (const float*)d_in[0];
  const float* key   = (const float*)d_in[1];
  const float* value = (const float*)d_in[2];
  const float* Wq    = (const float*)d_in[3];
  const float* bq    = (const float*)d_in[4];
  const float* Wk    = (const float*)d_in[5];
  const float* bk    = (const float*)d_in[6];
  const float* Wv    = (const float*)d_in[7];
  const float* bv    = (const float*)d_in[8];
  const float* Wo    = (const float*)d_in[9];
  const float* bo    = (const float*)d_in[10];
  float* out = (float*)d_out;

  const size_t NBIG = (size_t)1 << 23;   // 8192*1024
  const size_t NW   = (size_t)1 << 20;   // 1024*1024
  u16* Xq  = (u16*)d_ws;
  u16* Xk  = Xq  + NBIG;
  u16* Xv  = Xk  + NBIG;
  u16* Wqb = Xv  + NBIG;
  u16* Wkb = Wqb + NW;
  u16* Wvb = Wkb + NW;
  u16* Wob = Wvb + NW;
  u16* Qb  = Wob + NW;
  u16* Kb  = Qb  + NBIG;
  u16* Vb  = Kb  + NBIG;
  u16* Oa  = Vb  + NBIG;                 // total 120 MiB

  cvt_bf16<<<2048, 256, 0, stream>>>(query, Xq, (int)(NBIG / 4));
  cvt_bf16<<<2048, 256, 0, stream>>>(key,   Xk, (int)(NBIG / 4));
  cvt_bf16<<<2048, 256, 0, stream>>>(value, Xv, (int)(NBIG / 4));
  cvt_bf16<<<512,  256, 0, stream>>>(Wq, Wqb, (int)(NW / 4));
  cvt_bf16<<<512,  256, 0, stream>>>(Wk, Wkb, (int)(NW / 4));
  cvt_bf16<<<512,  256, 0, stream>>>(Wv, Wvb, (int)(NW / 4));
  cvt_bf16<<<512,  256, 0, stream>>>(Wo, Wob, (int)(NW / 4));

  // batched QKV projection: one dispatch, grid.z selects the set
  gemm_qkv<<<dim3(MROWS / 128, EMBED / 128, 3), 256, 0, stream>>>(
      Xq, Xk, Xv, Wqb, Wkb, Wvb, bq, bk, bv, Qb, Kb, Vb,
      0.125f * LOG2E);   // fold softmax scale + log2e into Q

  attn_mfma<<<dim3(SEQL / 128, BATCH * HEADS), 256, 0, stream>>>(Qb, Kb, Vb, Oa);

  gemm_out<<<dim3(MROWS / 128, EMBED / 128), 256, 0, stream>>>(Oa, Wob, bo, out);
}